// Round 4
// baseline (36.663 us; speedup 1.0000x reference)
//
#include <hip/hip_runtime.h>

namespace {

constexpr int JN = 21;   // joints
constexpr int BN = 20;   // bones
constexpr int FR = 32;   // frames per block

constexpr float F_F  = 512.0f;
constexpr float PX_F = 512.0f;
constexpr float PY_F = 288.0f;
constexpr float EPS_F = 1e-8f;

// weights folded with per-loss divisors
constexpr float WPROJ   = 0.25f / (2.0f * 21.0f);
constexpr float WLIFT   = 0.25f / (3.0f * 21.0f);
constexpr float WBONE   = 0.25f / 20.0f;
constexpr float WSMOOTH = 0.25f / (3.0f * 21.0f);

// LDS layout in floats (each region 16B-aligned: offsets % 4 == 0)
constexpr int OFF_POSE = 0;                  // (FR+2)*63 = 2142 -> pad 2144
constexpr int OFF_B2D  = 2144;               // FR*42 = 1344
constexpr int OFF_LIFT = 2144 + 1344;        // FR*60 = 1920
constexpr int OFF_M    = 3488 + 1920;        // FR*9  = 288
constexpr int OFF_MC   = 5408 + 288;         // FR*3  = 96
constexpr int POOL     = 5696 + 96;          // 5792 floats = 23168 B

__device__ __forceinline__ double block_reduce(double val) {
    __shared__ double smem[16];
    const int lane = threadIdx.x & 63;
    const int wid  = threadIdx.x >> 6;
    #pragma unroll
    for (int off = 32; off > 0; off >>= 1)
        val += __shfl_down(val, off, 64);
    if (lane == 0) smem[wid] = val;
    __syncthreads();
    if (wid == 0) {
        const int nw = blockDim.x >> 6;
        val = (lane < nw) ? smem[lane] : 0.0;
        #pragma unroll
        for (int off = 32; off > 0; off >>= 1)
            val += __shfl_down(val, off, 64);
    }
    return val;
}

__global__ __launch_bounds__(256) void pose_loss_kernel(
    const float* __restrict__ pose3d,      // (W+1, 3, 21)
    const float* __restrict__ bone_2d,     // (W, 2, 21)
    const float* __restrict__ lift_dirs,   // (W, 3, 20)
    const float* __restrict__ R_drone,     // (W, 3, 3)
    const float* __restrict__ C_drone,     // (W, 3, 1)
    const float* __restrict__ bone_len,    // (20,)
    const float* __restrict__ R_cam,       // (3,3)
    float* __restrict__ partials,          // (gridDim.x,)
    int W)
{
    __shared__ alignas(16) float pool[POOL];

    const int tid = threadIdx.x;
    const int w0  = blockIdx.x * FR;
    const int nF  = min(FR, W - w0);              // frames for per-frame arrays
    const int nPoseF = min(FR + 2, W + 1 - w0);   // pose frames incl. halo

    // ---------- stage everything through LDS with float4 loads ----------
    // all region global offsets are multiples of 4 floats (w0 % 32 == 0)
    {
        auto stage = [&](float* dst, const float* src, int nfl) {
            const int n4 = nfl >> 2;
            const float4* s4 = (const float4*)src;
            float4* d4 = (float4*)dst;
            for (int i = tid; i < n4; i += 256) d4[i] = s4[i];
            for (int i = (n4 << 2) + tid; i < nfl; i += 256) dst[i] = src[i];
        };
        stage(pool + OFF_POSE, pose3d    + (size_t)w0 * 63, nPoseF * 63);
        stage(pool + OFF_B2D,  bone_2d   + (size_t)w0 * 42, nF * 42);
        stage(pool + OFF_LIFT, lift_dirs + (size_t)w0 * 60, nF * 60);
        stage(pool + OFF_M,    R_drone   + (size_t)w0 * 9,  nF * 9);
        stage(pool + OFF_MC,   C_drone   + (size_t)w0 * 3,  nF * 3);
    }
    __syncthreads();

    // ---------- per-frame precompute: M = R_cam @ Rd^T, MC = M @ C ----------
    if (tid < nF) {
        float Rd[9];
        #pragma unroll
        for (int k = 0; k < 9; ++k) Rd[k] = pool[OFF_M + tid * 9 + k];
        float rc[9];
        #pragma unroll
        for (int k = 0; k < 9; ++k) rc[k] = R_cam[k];
        float M[9];
        #pragma unroll
        for (int i = 0; i < 3; ++i)
            #pragma unroll
            for (int k = 0; k < 3; ++k)
                M[i * 3 + k] = rc[i * 3 + 0] * Rd[k * 3 + 0]
                             + rc[i * 3 + 1] * Rd[k * 3 + 1]
                             + rc[i * 3 + 2] * Rd[k * 3 + 2];
        const float C0 = pool[OFF_MC + tid * 3 + 0];
        const float C1 = pool[OFF_MC + tid * 3 + 1];
        const float C2 = pool[OFF_MC + tid * 3 + 2];
        #pragma unroll
        for (int k = 0; k < 9; ++k) pool[OFF_M + tid * 9 + k] = M[k];
        #pragma unroll
        for (int i = 0; i < 3; ++i)
            pool[OFF_MC + tid * 3 + i] =
                M[i * 3 + 0] * C0 + M[i * 3 + 1] * C1 + M[i * 3 + 2] * C2;
    }
    __syncthreads();

    // ---------- compute (all operands in LDS; bone_len via L1) ----------
    float partial = 0.0f;
    const int nItems = nF * JN;
    for (int idx = tid; idx < nItems; idx += 256) {
        const int wl = idx / JN;
        const int j  = idx - wl * JN;
        const int w  = w0 + wl;

        const float* P1 = pool + OFF_POSE + (wl + 1) * 63;   // frame w+1
        const float p1x = P1[j];
        const float p1y = P1[JN + j];
        const float p1z = P1[2 * JN + j];

        // projection loss
        {
            const float* M  = pool + OFF_M  + wl * 9;
            const float* MC = pool + OFF_MC + wl * 3;
            const float c0 = M[0] * p1x + M[1] * p1y + M[2] * p1z - MC[0];
            const float c1 = M[3] * p1x + M[4] * p1y + M[5] * p1z - MC[1];
            const float c2 = M[6] * p1x + M[7] * p1y + M[8] * p1z - MC[2];
            const float invz = 1.0f / c2;
            const float u = F_F * c0 * invz + PX_F;
            const float v = F_F * c1 * invz + PY_F;
            const float du = u - pool[OFF_B2D + wl * 42 + j];
            const float dv = v - pool[OFF_B2D + wl * 42 + JN + j];
            partial += WPROJ * (du * du + dv * dv);
        }

        // lift + bone losses; bone_connections is statically (j+1, j)
        if (j < BN) {
            const int b0 = j + 1;
            const int b1 = j;
            {
                const float ax = P1[b0]          - P1[b1];
                const float ay = P1[JN + b0]     - P1[JN + b1];
                const float az = P1[2 * JN + b0] - P1[2 * JN + b1];
                const float inv = 1.0f / (sqrtf(ax * ax + ay * ay + az * az) + EPS_F);
                const float lx = pool[OFF_LIFT + wl * 60 + j]           - ax * inv;
                const float ly = pool[OFF_LIFT + wl * 60 + BN + j]      - ay * inv;
                const float lz = pool[OFF_LIFT + wl * 60 + 2 * BN + j]  - az * inv;
                partial += WLIFT * (lx * lx + ly * ly + lz * lz);
            }
            const float blj = bone_len[j];
            {
                const float* P0 = pool + OFF_POSE + wl * 63;   // frame w
                const float bx = P0[b0]          - P0[b1];
                const float by = P0[JN + b0]     - P0[JN + b1];
                const float bz = P0[2 * JN + b0] - P0[2 * JN + b1];
                const float bl = bx * bx + by * by + bz * bz;
                const float e = blj - bl;
                partial += WBONE * (e * e);
            }
            if (w == W - 1) {                                  // frame W == P1 here
                const float bx = P1[b0]          - P1[b1];
                const float by = P1[JN + b0]     - P1[JN + b1];
                const float bz = P1[2 * JN + b0] - P1[2 * JN + b1];
                const float bl = bx * bx + by * by + bz * bz;
                const float e = blj - bl;
                partial += WBONE * (e * e);
            }
        }

        // smoothness (t = w)
        if (w < W - 1) {
            const float* P0 = pool + OFF_POSE + wl * 63;
            const float* P2 = pool + OFF_POSE + (wl + 2) * 63;
            const float sx = P2[j]          - 2.0f * p1x + P0[j];
            const float sy = P2[JN + j]     - 2.0f * p1y + P0[JN + j];
            const float sz = P2[2 * JN + j] - 2.0f * p1z + P0[2 * JN + j];
            partial += WSMOOTH * (sx * sx + sy * sy + sz * sz);
        }
    }

    const double bsum = block_reduce((double)partial);
    if (tid == 0) partials[blockIdx.x] = (float)bsum;
}

__global__ __launch_bounds__(256) void final_reduce_kernel(
    const float* __restrict__ partials, float* __restrict__ out, int n)
{
    double v = 0.0;
    for (int i = threadIdx.x; i < n; i += blockDim.x)
        v += (double)partials[i];
    v = block_reduce(v);
    if (threadIdx.x == 0) out[0] = (float)v;
}

}  // namespace

extern "C" void kernel_launch(void* const* d_in, const int* in_sizes, int n_in,
                              void* d_out, int out_size, void* d_ws, size_t ws_size,
                              hipStream_t stream) {
    const float* pose3d    = (const float*)d_in[0];
    const float* bone_2d   = (const float*)d_in[1];
    const float* lift_dirs = (const float*)d_in[2];
    const float* R_drone   = (const float*)d_in[3];
    const float* C_drone   = (const float*)d_in[4];
    const float* bone_len  = (const float*)d_in[5];
    const float* R_cam     = (const float*)d_in[6];
    float* out = (float*)d_out;
    float* partials = (float*)d_ws;

    const int W = in_sizes[3] / 9;       // R_drone is (W,3,3)
    const int grid = (W + FR - 1) / FR;  // 4096 for W=131072

    pose_loss_kernel<<<grid, 256, 0, stream>>>(
        pose3d, bone_2d, lift_dirs, R_drone, C_drone, bone_len, R_cam, partials, W);
    final_reduce_kernel<<<1, 256, 0, stream>>>(partials, out, grid);
}

// Round 5
// 27.783 us; speedup vs baseline: 1.3196x; 1.3196x over previous
//
#include <hip/hip_runtime.h>

namespace {

constexpr int JN = 21;   // joints
constexpr int BN = 20;   // bones
constexpr int FR = 64;   // frames per block

constexpr float F_F  = 512.0f;
constexpr float PX_F = 512.0f;
constexpr float PY_F = 288.0f;
constexpr float EPS_F = 1e-8f;

// weights folded with per-loss divisors
constexpr float WPROJ   = 0.25f / (2.0f * 21.0f);
constexpr float WLIFT   = 0.25f / (3.0f * 21.0f);
constexpr float WBONE   = 0.25f / 20.0f;
constexpr float WSMOOTH = 0.25f / (3.0f * 21.0f);

__device__ __forceinline__ double block_reduce(double val) {
    __shared__ double smem[16];
    const int lane = threadIdx.x & 63;
    const int wid  = threadIdx.x >> 6;
    #pragma unroll
    for (int off = 32; off > 0; off >>= 1)
        val += __shfl_down(val, off, 64);
    if (lane == 0) smem[wid] = val;
    __syncthreads();
    if (wid == 0) {
        const int nw = blockDim.x >> 6;
        val = (lane < nw) ? smem[lane] : 0.0;
        #pragma unroll
        for (int off = 32; off > 0; off >>= 1)
            val += __shfl_down(val, off, 64);
    }
    return val;
}

__global__ __launch_bounds__(256) void pose_loss_kernel(
    const float* __restrict__ pose3d,      // (W+1, 3, 21)
    const float* __restrict__ bone_2d,     // (W, 2, 21)
    const float* __restrict__ lift_dirs,   // (W, 3, 20)
    const float* __restrict__ R_drone,     // (W, 3, 3)
    const float* __restrict__ C_drone,     // (W, 3, 1)
    const float* __restrict__ bone_len,    // (20,)
    const float* __restrict__ R_cam,       // (3,3)
    float* __restrict__ partials,          // (gridDim.x,)
    int W)
{
    // 4160 + 576 + 192 floats = 19712 B -> 8 blocks/CU
    __shared__ alignas(16) float s_pose[(FR + 2) * 63 + 2];
    __shared__ alignas(16) float s_M[FR * 9];
    __shared__ alignas(16) float s_MC[FR * 3];

    const int tid = threadIdx.x;
    const int w0  = blockIdx.x * FR;
    const int nF  = min(FR, W - w0);
    const int nPoseF = min(FR + 2, W + 1 - w0);

    // ---------- stage reused data (pose halo, R, C) with float4 loads ----------
    {
        const float* src = pose3d + (size_t)w0 * 63;
        const int nfl = nPoseF * 63;
        const int n4 = nfl >> 2;
        const float4* s4 = (const float4*)src;
        float4* d4 = (float4*)s_pose;
        for (int i = tid; i < n4; i += 256) d4[i] = s4[i];
        for (int i = (n4 << 2) + tid; i < nfl; i += 256) s_pose[i] = src[i];
    }
    {
        const float* src = R_drone + (size_t)w0 * 9;
        const int nfl = nF * 9;
        const int n4 = nfl >> 2;
        const float4* s4 = (const float4*)src;
        float4* d4 = (float4*)s_M;
        for (int i = tid; i < n4; i += 256) d4[i] = s4[i];
        for (int i = (n4 << 2) + tid; i < nfl; i += 256) s_M[i] = src[i];
    }
    {
        const float* src = C_drone + (size_t)w0 * 3;
        const int nfl = nF * 3;
        const int n4 = nfl >> 2;
        const float4* s4 = (const float4*)src;
        float4* d4 = (float4*)s_MC;
        for (int i = tid; i < n4; i += 256) d4[i] = s4[i];
        for (int i = (n4 << 2) + tid; i < nfl; i += 256) s_MC[i] = src[i];
    }
    __syncthreads();

    // ---------- per-frame precompute: M = R_cam @ Rd^T, MC = M @ C ----------
    if (tid < nF) {
        float Rd[9];
        #pragma unroll
        for (int k = 0; k < 9; ++k) Rd[k] = s_M[tid * 9 + k];
        float rc[9];
        #pragma unroll
        for (int k = 0; k < 9; ++k) rc[k] = R_cam[k];   // uniform -> s_load
        float M[9];
        #pragma unroll
        for (int i = 0; i < 3; ++i)
            #pragma unroll
            for (int k = 0; k < 3; ++k)
                M[i * 3 + k] = rc[i * 3 + 0] * Rd[k * 3 + 0]
                             + rc[i * 3 + 1] * Rd[k * 3 + 1]
                             + rc[i * 3 + 2] * Rd[k * 3 + 2];
        const float C0 = s_MC[tid * 3 + 0];
        const float C1 = s_MC[tid * 3 + 1];
        const float C2 = s_MC[tid * 3 + 2];
        #pragma unroll
        for (int k = 0; k < 9; ++k) s_M[tid * 9 + k] = M[k];
        #pragma unroll
        for (int i = 0; i < 3; ++i)
            s_MC[tid * 3 + i] = M[i * 3 + 0] * C0 + M[i * 3 + 1] * C1 + M[i * 3 + 2] * C2;
    }
    __syncthreads();

    // ---------- compute: pose/M/MC from LDS, bone_2d/lift streamed ----------
    float partial = 0.0f;

    auto body = [&](int idx) {
        const int wl = idx / JN;
        const int j  = idx - wl * JN;
        const int w  = w0 + wl;

        const float* P1 = s_pose + (wl + 1) * 63;   // frame w+1
        const float p1x = P1[j];
        const float p1y = P1[JN + j];
        const float p1z = P1[2 * JN + j];

        // projection loss (streams bone_2d)
        {
            const float* M  = s_M  + wl * 9;
            const float* MC = s_MC + wl * 3;
            const float c0 = M[0] * p1x + M[1] * p1y + M[2] * p1z - MC[0];
            const float c1 = M[3] * p1x + M[4] * p1y + M[5] * p1z - MC[1];
            const float c2 = M[6] * p1x + M[7] * p1y + M[8] * p1z - MC[2];
            const float invz = 1.0f / c2;
            const float u = F_F * c0 * invz + PX_F;
            const float v = F_F * c1 * invz + PY_F;
            const float du = u - bone_2d[(size_t)w * 42 + j];
            const float dv = v - bone_2d[(size_t)w * 42 + JN + j];
            partial += WPROJ * (du * du + dv * dv);
        }

        // lift + bone losses; bone_connections is statically (j+1, j)
        if (j < BN) {
            const int b0 = j + 1;
            const int b1 = j;
            {
                const float ax = P1[b0]          - P1[b1];
                const float ay = P1[JN + b0]     - P1[JN + b1];
                const float az = P1[2 * JN + b0] - P1[2 * JN + b1];
                const float inv = 1.0f / (sqrtf(ax * ax + ay * ay + az * az) + EPS_F);
                const float lx = lift_dirs[(size_t)w * 60 + j]           - ax * inv;
                const float ly = lift_dirs[(size_t)w * 60 + BN + j]      - ay * inv;
                const float lz = lift_dirs[(size_t)w * 60 + 2 * BN + j]  - az * inv;
                partial += WLIFT * (lx * lx + ly * ly + lz * lz);
            }
            const float blj = bone_len[j];
            {
                const float* P0 = s_pose + wl * 63;   // frame w
                const float bx = P0[b0]          - P0[b1];
                const float by = P0[JN + b0]     - P0[JN + b1];
                const float bz = P0[2 * JN + b0] - P0[2 * JN + b1];
                const float bl = bx * bx + by * by + bz * bz;
                const float e = blj - bl;
                partial += WBONE * (e * e);
            }
            if (w == W - 1) {                         // frame W == P1 here
                const float bx = P1[b0]          - P1[b1];
                const float by = P1[JN + b0]     - P1[JN + b1];
                const float bz = P1[2 * JN + b0] - P1[2 * JN + b1];
                const float bl = bx * bx + by * by + bz * bz;
                const float e = blj - bl;
                partial += WBONE * (e * e);
            }
        }

        // smoothness (t = w)
        if (w < W - 1) {
            const float* P0 = s_pose + wl * 63;
            const float* P2 = s_pose + (wl + 2) * 63;
            const float sx = P2[j]          - 2.0f * p1x + P0[j];
            const float sy = P2[JN + j]     - 2.0f * p1y + P0[JN + j];
            const float sz = P2[2 * JN + j] - 2.0f * p1z + P0[2 * JN + j];
            partial += WSMOOTH * (sx * sx + sy * sy + sz * sz);
        }
    };

    if (nF == FR) {
        // FR*JN = 1344 items = 5*256 + 64: fully unrolled -> deep MLP on streams
        #pragma unroll
        for (int k = 0; k < 5; ++k) body(tid + k * 256);
        if (tid < FR * JN - 5 * 256) body(5 * 256 + tid);
    } else {
        for (int idx = tid; idx < nF * JN; idx += 256) body(idx);
    }

    const double bsum = block_reduce((double)partial);
    if (tid == 0) partials[blockIdx.x] = (float)bsum;
}

__global__ __launch_bounds__(256) void final_reduce_kernel(
    const float* __restrict__ partials, float* __restrict__ out, int n)
{
    double v = 0.0;
    for (int i = threadIdx.x; i < n; i += blockDim.x)
        v += (double)partials[i];
    v = block_reduce(v);
    if (threadIdx.x == 0) out[0] = (float)v;
}

}  // namespace

extern "C" void kernel_launch(void* const* d_in, const int* in_sizes, int n_in,
                              void* d_out, int out_size, void* d_ws, size_t ws_size,
                              hipStream_t stream) {
    const float* pose3d    = (const float*)d_in[0];
    const float* bone_2d   = (const float*)d_in[1];
    const float* lift_dirs = (const float*)d_in[2];
    const float* R_drone   = (const float*)d_in[3];
    const float* C_drone   = (const float*)d_in[4];
    const float* bone_len  = (const float*)d_in[5];
    const float* R_cam     = (const float*)d_in[6];
    float* out = (float*)d_out;
    float* partials = (float*)d_ws;

    const int W = in_sizes[3] / 9;       // R_drone is (W,3,3)
    const int grid = (W + FR - 1) / FR;  // 2048 for W=131072

    pose_loss_kernel<<<grid, 256, 0, stream>>>(
        pose3d, bone_2d, lift_dirs, R_drone, C_drone, bone_len, R_cam, partials, W);
    final_reduce_kernel<<<1, 256, 0, stream>>>(partials, out, grid);
}